// Round 5
// baseline (100.450 us; speedup 1.0000x reference)
//
#include <hip/hip_runtime.h>

// AggregationRebuild fused: per block of 8 output rows x 1/8 column tile:
//   phase 1 (64 threads): resolve idx (int64/int32 autodetect), gather sim
//     (nontemporal - don't pollute the XCD-resident emb slice), softmax over
//     K=8 via 8-lane shuffles; tile-0 blocks write weights output.
//   phase 2 (256 threads): XCD-L2-tiled weighted gather-sum. tile = bid % 8
//     -> round-robin dispatch puts equal-residue blocks on the same XCD, so
//     each XCD's L2 holds one 4 MB column slice of emb. Nontemporal output
//     stores keep the slice resident.

typedef float f32x4 __attribute__((ext_vector_type(4)));

constexpr int N  = 2048;
constexpr int K  = 8;
constexpr int LD = 64 * 64;            // 4096 floats per row
constexpr float INV_TEMP = 2.0f;       // 1 / 0.5

constexpr int TILE   = 512;            // floats per column tile
constexpr int NTILES = LD / TILE;      // 8 == #XCDs
constexpr int RPB    = 8;              // rows per block

__global__ __launch_bounds__(256) void agg_rebuild_fused(
    const float* __restrict__ sim,     // [N, N]
    const float* __restrict__ emb,     // [N, LD]
    const int*   __restrict__ idx32,   // [N, K] int32 or int64 (detected)
    float* __restrict__ w_out,         // [N, K]
    float* __restrict__ rebuild) {     // [N, LD]
  const int tile = blockIdx.x & (NTILES - 1);
  const int rg   = blockIdx.x >> 3;    // row group
  const int r0   = rg * RPB;
  const int tid  = threadIdx.x;

  __shared__ float w_lds[RPB][K];
  __shared__ int   j_lds[RPB][K];
  __shared__ int   is64_s;

  // int64 vs int32 layout: values in [0, 2048), little-endian -> for int64
  // every odd int32 word is 0; for int32 random indices, P(all 8 zero) ~ 0.
  if (tid == 0) {
    int acc = idx32[1] | idx32[3] | idx32[5] | idx32[7] |
              idx32[9] | idx32[11] | idx32[13] | idx32[15];
    is64_s = (acc == 0) ? 1 : 0;
  }
  __syncthreads();

  // Phase 1: weights for this block's 8 rows (tid 0..63 = one wave,
  // 8-lane groups aligned so __shfl_xor(..,w=8) stays in-group).
  if (tid < RPB * K) {
    const int rl = tid >> 3;
    const int k  = tid & 7;
    const int flat = (r0 + rl) * K + k;
    const int j = is64_s ? idx32[2 * flat] : idx32[flat];
    const float s =
        __builtin_nontemporal_load(sim + (size_t)(r0 + rl) * N + j) * INV_TEMP;

    float m = s;
    m = fmaxf(m, __shfl_xor(m, 1, 8));
    m = fmaxf(m, __shfl_xor(m, 2, 8));
    m = fmaxf(m, __shfl_xor(m, 4, 8));
    const float e = expf(s - m);
    float sum = e;
    sum += __shfl_xor(sum, 1, 8);
    sum += __shfl_xor(sum, 2, 8);
    sum += __shfl_xor(sum, 4, 8);
    const float w = e / sum;

    w_lds[rl][k] = w;
    j_lds[rl][k] = j;
    if (tile == 0) w_out[flat] = w;    // exactly one writer per weight
  }
  __syncthreads();

  // Phase 2: weighted gather-sum over this column tile.
  const int c   = tid & 127;           // float4 chunk within tile (128 chunks)
  const int sub = tid >> 7;            // 0..1 : two rows in flight per pass
  const int col = tile * TILE + c * 4;

#pragma unroll
  for (int it = 0; it < RPB / 2; ++it) {
    const int rl = it * 2 + sub;
    float w[K];
    const f32x4* p[K];
#pragma unroll
    for (int k = 0; k < K; ++k) {
      w[k] = w_lds[rl][k];
      p[k] = reinterpret_cast<const f32x4*>(emb + (size_t)j_lds[rl][k] * LD + col);
    }
    f32x4 acc = (f32x4)(0.0f);
#pragma unroll
    for (int k = 0; k < K; ++k) {
      const f32x4 v = *p[k];
      acc += w[k] * v;
    }
    f32x4* o = reinterpret_cast<f32x4*>(rebuild + (size_t)(r0 + rl) * LD + col);
    __builtin_nontemporal_store(acc, o);
  }
}

extern "C" void kernel_launch(void* const* d_in, const int* in_sizes, int n_in,
                              void* d_out, int out_size, void* d_ws, size_t ws_size,
                              hipStream_t stream) {
  const float* sim = (const float*)d_in[0];
  const float* emb = (const float*)d_in[1];
  const int*   idx = (const int*)d_in[2];
  float* out     = (float*)d_out;
  float* w_out   = out;                       // [N, K]
  float* rebuild = out + (size_t)N * K;       // [N, LD]

  hipLaunchKernelGGL(agg_rebuild_fused, dim3((N / RPB) * NTILES), dim3(256),
                     0, stream, sim, emb, idx, w_out, rebuild);
}